// Round 1
// baseline (1607.037 us; speedup 1.0000x reference)
//
#include <hip/hip_runtime.h>

#define N_NODES 100000
#define N_EDGES 3200000

// ---- K0: deg init (self-loop weight 1.0) ----
__global__ void k_init_deg(float* __restrict__ deg) {
    int i = blockIdx.x * blockDim.x + threadIdx.x;
    if (i < N_NODES) deg[i] = 1.0f;
}

// ---- K1: deg[dst] += w ----
__global__ void k_deg(const int* __restrict__ dst, const float* __restrict__ w,
                      float* __restrict__ deg) {
    int e = blockIdx.x * blockDim.x + threadIdx.x;
    if (e < N_EDGES) atomicAdd(&deg[dst[e]], w[e]);
}

// ---- K2: dinv = rsqrt(deg) (in-place); agg1[i] = dinv^2 * x[i] (self loop) ----
__global__ void k_dinv_agg(const float* __restrict__ x, float* __restrict__ deg_dinv,
                           float* __restrict__ agg) {
    int i = blockIdx.x * blockDim.x + threadIdx.x;
    if (i >= N_NODES) return;
    float di = rsqrtf(deg_dinv[i]);
    deg_dinv[i] = di;
    float s = di * di;
    const float4* xr = (const float4*)(x + (size_t)i * 16);
    float4* ar = (float4*)(agg + (size_t)i * 16);
#pragma unroll
    for (int k = 0; k < 4; k++) {
        float4 v = xr[k];
        v.x *= s; v.y *= s; v.z *= s; v.w *= s;
        ar[k] = v;
    }
}

// ---- K3/K5: edge scatter, 4 threads per edge (each does 4 channels) ----
__global__ void k_scatter(const int* __restrict__ src, const int* __restrict__ dst,
                          const float* __restrict__ w, const float* __restrict__ dinv,
                          const float* __restrict__ feat, float* __restrict__ out) {
    int t = blockIdx.x * blockDim.x + threadIdx.x;
    int e = t >> 2;
    int c4 = (t & 3) * 4;
    if (e >= N_EDGES) return;
    int s = src[e], d = dst[e];
    float nrm = dinv[s] * w[e] * dinv[d];
    float4 v = *(const float4*)(feat + (size_t)s * 16 + c4);
    float* o = out + (size_t)d * 16 + c4;
    atomicAdd(o + 0, nrm * v.x);
    atomicAdd(o + 1, nrm * v.y);
    atomicAdd(o + 2, nrm * v.z);
    atomicAdd(o + 3, nrm * v.w);
}

// ---- K4: fused per-node MLP: o1 = relu(agg1@W1+b1); h2 = o1@W2 (overwrites agg);
//          out init = dinv^2*h2 + b2 (self loop + bias). One wave per node. ----
__global__ __launch_bounds__(256) void k_mlp(float* __restrict__ agg,  // in: agg1, out: h2
                                             const float* __restrict__ W1,
                                             const float* __restrict__ b1,
                                             const float* __restrict__ W2,
                                             const float* __restrict__ b2,
                                             const float* __restrict__ dinv,
                                             float* __restrict__ out) {
    __shared__ float o1s[4][128];
    int wave = threadIdx.x >> 6;
    int lane = threadIdx.x & 63;
    int node = blockIdx.x * 4 + wave;   // N_NODES % 4 == 0 -> all waves active
    const float* f = agg + (size_t)node * 16;
    float fv[16];
#pragma unroll
    for (int k = 0; k < 4; k++) {
        float4 v = ((const float4*)f)[k];
        fv[4 * k + 0] = v.x; fv[4 * k + 1] = v.y; fv[4 * k + 2] = v.z; fv[4 * k + 3] = v.w;
    }
    float a = b1[2 * lane], b = b1[2 * lane + 1];
#pragma unroll
    for (int k = 0; k < 16; k++) {
        float2 wv = *(const float2*)(W1 + k * 128 + 2 * lane);
        a = fmaf(fv[k], wv.x, a);
        b = fmaf(fv[k], wv.y, b);
    }
    o1s[wave][2 * lane + 0] = fmaxf(a, 0.0f);
    o1s[wave][2 * lane + 1] = fmaxf(b, 0.0f);
    __syncthreads();
    int c = lane & 15, g = lane >> 4;
    float p = 0.0f;
#pragma unroll
    for (int k = 0; k < 32; k++) {
        int kk = g * 32 + k;
        p = fmaf(o1s[wave][kk], W2[kk * 16 + c], p);
    }
    p += __shfl_down(p, 16, 64);
    p += __shfl_down(p, 32, 64);
    __syncthreads();   // protect o1s before anyone could loop (none) & order h2 write after reads
    if (lane < 16) {
        float h2v = p;
        agg[(size_t)node * 16 + c] = h2v;          // h2 row overwrites agg1 row (same node, safe)
        float di = dinv[node];
        out[(size_t)node * 16 + c] = di * di * h2v + b2[c];
    }
}

extern "C" void kernel_launch(void* const* d_in, const int* in_sizes, int n_in,
                              void* d_out, int out_size, void* d_ws, size_t ws_size,
                              hipStream_t stream) {
    const float* x  = (const float*)d_in[0];
    const int*   ei = (const int*)d_in[1];          // [2, E] int32
    const float* w  = (const float*)d_in[2];
    const float* W1 = (const float*)d_in[3];
    const float* b1 = (const float*)d_in[4];
    const float* W2 = (const float*)d_in[5];
    const float* b2 = (const float*)d_in[6];
    float* out = (float*)d_out;

    const int* src = ei;
    const int* dst = ei + N_EDGES;

    float* deg_dinv = (float*)d_ws;                       // N floats (deg then dinv in-place)
    float* agg      = (float*)d_ws + N_NODES;             // N*16 floats (agg1 then h2 in-place)

    const int B = 256;
    k_init_deg<<<(N_NODES + B - 1) / B, B, 0, stream>>>(deg_dinv);
    k_deg<<<(N_EDGES + B - 1) / B, B, 0, stream>>>(dst, w, deg_dinv);
    k_dinv_agg<<<(N_NODES + B - 1) / B, B, 0, stream>>>(x, deg_dinv, agg);
    k_scatter<<<(N_EDGES * 4 + B - 1) / B, B, 0, stream>>>(src, dst, w, deg_dinv, x, agg);
    // wait: scatter layer1 must add norm * x[src] into agg1 -> feat = x, out = agg.  (above)
    k_mlp<<<N_NODES / 4, B, 0, stream>>>(agg, W1, b1, W2, b2, deg_dinv, out);
    k_scatter<<<(N_EDGES * 4 + B - 1) / B, B, 0, stream>>>(src, dst, w, deg_dinv, agg, out);
}

// Round 2
// 782.913 us; speedup vs baseline: 2.0526x; 2.0526x over previous
//
#include <hip/hip_runtime.h>

#define N_NODES 100000
#define N_EDGES 3200000
#define N_PAD   100096          // padded node count (keeps perm 8B-aligned)
#define SCAN_CHUNK 2048         // 256 threads x 8 items
#define SCAN_BLOCKS ((N_NODES + SCAN_CHUNK - 1) / SCAN_CHUNK)   // 49

// ===================== shared small kernels =====================

// deg init (self-loop weight 1.0) + cnt zero
__global__ void k_init(float* __restrict__ deg, int* __restrict__ cnt) {
    int i = blockIdx.x * blockDim.x + threadIdx.x;
    if (i < N_NODES) { deg[i] = 1.0f; if (cnt) cnt[i] = 0; }
}

// deg[dst] += w ; cnt[dst] += 1
__global__ void k_degcnt(const int* __restrict__ dst, const float* __restrict__ w,
                         float* __restrict__ deg, int* __restrict__ cnt) {
    int e = blockIdx.x * blockDim.x + threadIdx.x;
    if (e < N_EDGES) {
        int d = dst[e];
        atomicAdd(&deg[d], w[e]);
        if (cnt) atomicAdd(&cnt[d], 1);
    }
}

// dinv = rsqrt(deg) in-place; agg1[i] = dinv^2 * x[i]  (self-loop term of layer 1)
__global__ void k_dinv_agg(const float* __restrict__ x, float* __restrict__ deg_dinv,
                           float* __restrict__ agg) {
    int i = blockIdx.x * blockDim.x + threadIdx.x;
    if (i >= N_NODES) return;
    float di = rsqrtf(deg_dinv[i]);
    deg_dinv[i] = di;
    float s = di * di;
    const float4* xr = (const float4*)(x + (size_t)i * 16);
    float4* ar = (float4*)(agg + (size_t)i * 16);
#pragma unroll
    for (int k = 0; k < 4; k++) {
        float4 v = xr[k];
        v.x *= s; v.y *= s; v.z *= s; v.w *= s;
        ar[k] = v;
    }
}

// ===================== CSR build =====================

// block-local exclusive scan of cnt -> rowptr, per-block total -> bsum
__global__ __launch_bounds__(256) void k_scan1(const int* __restrict__ cnt,
                                               int* __restrict__ rowptr,
                                               int* __restrict__ bsum) {
    __shared__ int ts[256];
    int tid = threadIdx.x;
    int base = blockIdx.x * SCAN_CHUNK + tid * 8;
    int v[8]; int s = 0;
#pragma unroll
    for (int k = 0; k < 8; k++) {
        int idx = base + k;
        v[k] = (idx < N_NODES) ? cnt[idx] : 0;
        s += v[k];
    }
    ts[tid] = s;
    __syncthreads();
    for (int off = 1; off < 256; off <<= 1) {
        int t = (tid >= off) ? ts[tid - off] : 0;
        __syncthreads();
        ts[tid] += t;
        __syncthreads();
    }
    int run = ts[tid] - s;          // exclusive prefix for this thread within block
#pragma unroll
    for (int k = 0; k < 8; k++) {
        int idx = base + k;
        if (idx < N_NODES) rowptr[idx] = run;
        run += v[k];
    }
    if (tid == 255) bsum[blockIdx.x] = ts[255];   // block total
}

// serial exclusive scan of block sums (tiny)
__global__ void k_scan2(int* __restrict__ bsum) {
    if (threadIdx.x == 0 && blockIdx.x == 0) {
        int run = 0;
        for (int g = 0; g < SCAN_BLOCKS; g++) { int t = bsum[g]; bsum[g] = run; run += t; }
    }
}

// add block offsets; set rowptr[N] = E
__global__ __launch_bounds__(256) void k_scan3(int* __restrict__ rowptr,
                                               const int* __restrict__ bsum) {
    int tid = threadIdx.x;
    int base = blockIdx.x * SCAN_CHUNK + tid * 8;
    int off = bsum[blockIdx.x];
#pragma unroll
    for (int k = 0; k < 8; k++) {
        int idx = base + k;
        if (idx < N_NODES) rowptr[idx] += off;
    }
    if (blockIdx.x == 0 && tid == 0) rowptr[N_NODES] = N_EDGES;
}

// scatter edges into CSR slots; perm[pos] = {src, norm}
__global__ void k_fill(const int* __restrict__ src, const int* __restrict__ dst,
                       const float* __restrict__ w, const float* __restrict__ dinv,
                       const int* __restrict__ rowptr, int* __restrict__ cnt,
                       int2* __restrict__ perm) {
    int e = blockIdx.x * blockDim.x + threadIdx.x;
    if (e >= N_EDGES) return;
    int s = src[e], d = dst[e];
    float nrm = dinv[s] * w[e] * dinv[d];
    int r = atomicSub(&cnt[d], 1) - 1;
    int pos = rowptr[d] + r;
    perm[pos] = make_int2(s, __float_as_int(nrm));
}

// ===================== gather aggregation (no atomics) =====================
// one wave per node: 64 lanes = 4 edge-slots x 16 channels; out[n*16+c] += sum
__global__ __launch_bounds__(256) void k_gather(const int2* __restrict__ perm,
                                                const int* __restrict__ rowptr,
                                                const float* __restrict__ feat,
                                                float* __restrict__ out) {
    int wave = threadIdx.x >> 6, lane = threadIdx.x & 63;
    int node = blockIdx.x * 4 + wave;            // N_NODES % 4 == 0
    int c = lane & 15, eo = lane >> 4;
    int beg = rowptr[node], end = rowptr[node + 1];
    float acc = 0.0f;
    for (int j = beg + eo; j < end; j += 4) {
        int2 ed = perm[j];
        acc = fmaf(__int_as_float(ed.y), feat[(size_t)ed.x * 16 + c], acc);
    }
    acc += __shfl_xor(acc, 16, 64);
    acc += __shfl_xor(acc, 32, 64);
    if (lane < 16) out[(size_t)node * 16 + c] += acc;
}

// ===================== fused per-node MLP =====================
// o1 = relu(agg1@W1+b1); h2 = o1@W2 (overwrites agg); out = dinv^2*h2 + b2
__global__ __launch_bounds__(256) void k_mlp(float* __restrict__ agg,
                                             const float* __restrict__ W1,
                                             const float* __restrict__ b1,
                                             const float* __restrict__ W2,
                                             const float* __restrict__ b2,
                                             const float* __restrict__ dinv,
                                             float* __restrict__ out) {
    __shared__ float o1s[4][128];
    int wave = threadIdx.x >> 6;
    int lane = threadIdx.x & 63;
    int node = blockIdx.x * 4 + wave;
    const float* f = agg + (size_t)node * 16;
    float fv[16];
#pragma unroll
    for (int k = 0; k < 4; k++) {
        float4 v = ((const float4*)f)[k];
        fv[4 * k + 0] = v.x; fv[4 * k + 1] = v.y; fv[4 * k + 2] = v.z; fv[4 * k + 3] = v.w;
    }
    float a = b1[2 * lane], b = b1[2 * lane + 1];
#pragma unroll
    for (int k = 0; k < 16; k++) {
        float2 wv = *(const float2*)(W1 + k * 128 + 2 * lane);
        a = fmaf(fv[k], wv.x, a);
        b = fmaf(fv[k], wv.y, b);
    }
    o1s[wave][2 * lane + 0] = fmaxf(a, 0.0f);
    o1s[wave][2 * lane + 1] = fmaxf(b, 0.0f);
    __syncthreads();
    int c = lane & 15, g = lane >> 4;
    float p = 0.0f;
#pragma unroll
    for (int k = 0; k < 32; k++) {
        int kk = g * 32 + k;
        p = fmaf(o1s[wave][kk], W2[kk * 16 + c], p);
    }
    p += __shfl_down(p, 16, 64);
    p += __shfl_down(p, 32, 64);
    __syncthreads();
    if (lane < 16) {
        float h2v = p;
        agg[(size_t)node * 16 + c] = h2v;
        float di = dinv[node];
        out[(size_t)node * 16 + c] = di * di * h2v + b2[c];
    }
}

// ===================== fallback (round-1 atomic scatter) =====================
__global__ void k_scatter(const int* __restrict__ src, const int* __restrict__ dst,
                          const float* __restrict__ w, const float* __restrict__ dinv,
                          const float* __restrict__ feat, float* __restrict__ out) {
    int t = blockIdx.x * blockDim.x + threadIdx.x;
    int e = t >> 2;
    int c4 = (t & 3) * 4;
    if (e >= N_EDGES) return;
    int s = src[e], d = dst[e];
    float nrm = dinv[s] * w[e] * dinv[d];
    float4 v = *(const float4*)(feat + (size_t)s * 16 + c4);
    float* o = out + (size_t)d * 16 + c4;
    atomicAdd(o + 0, nrm * v.x);
    atomicAdd(o + 1, nrm * v.y);
    atomicAdd(o + 2, nrm * v.z);
    atomicAdd(o + 3, nrm * v.w);
}

extern "C" void kernel_launch(void* const* d_in, const int* in_sizes, int n_in,
                              void* d_out, int out_size, void* d_ws, size_t ws_size,
                              hipStream_t stream) {
    const float* x  = (const float*)d_in[0];
    const int*   ei = (const int*)d_in[1];          // [2, E] int32
    const float* w  = (const float*)d_in[2];
    const float* W1 = (const float*)d_in[3];
    const float* b1 = (const float*)d_in[4];
    const float* W2 = (const float*)d_in[5];
    const float* b2 = (const float*)d_in[6];
    float* out = (float*)d_out;

    const int* src = ei;
    const int* dst = ei + N_EDGES;

    // workspace layout
    float* deg_dinv = (float*)d_ws;                         // [N_PAD]
    int*   cnt      = (int*)(deg_dinv + N_PAD);             // [N_PAD]
    int*   rowptr   = cnt + N_PAD;                          // [N_PAD] (uses N+1)
    int*   bsum     = rowptr + N_PAD;                       // [64]
    float* agg      = (float*)(bsum + 64);                  // [N*16]
    int2*  perm     = (int2*)(agg + (size_t)N_NODES * 16);  // [E]
    const size_t WS_NEEDED = ((size_t)N_PAD * 3 + 64 + (size_t)N_NODES * 16) * 4
                             + (size_t)N_EDGES * 8;

    const int B = 256;
    if (ws_size >= WS_NEEDED) {
        k_init<<<(N_NODES + B - 1) / B, B, 0, stream>>>(deg_dinv, cnt);
        k_degcnt<<<(N_EDGES + B - 1) / B, B, 0, stream>>>(dst, w, deg_dinv, cnt);
        k_dinv_agg<<<(N_NODES + B - 1) / B, B, 0, stream>>>(x, deg_dinv, agg);
        k_scan1<<<SCAN_BLOCKS, 256, 0, stream>>>(cnt, rowptr, bsum);
        k_scan2<<<1, 64, 0, stream>>>(bsum);
        k_scan3<<<SCAN_BLOCKS, 256, 0, stream>>>(rowptr, bsum);
        k_fill<<<(N_EDGES + B - 1) / B, B, 0, stream>>>(src, dst, w, deg_dinv,
                                                        rowptr, cnt, perm);
        k_gather<<<N_NODES / 4, B, 0, stream>>>(perm, rowptr, x, agg);
        k_mlp<<<N_NODES / 4, B, 0, stream>>>(agg, W1, b1, W2, b2, deg_dinv, out);
        k_gather<<<N_NODES / 4, B, 0, stream>>>(perm, rowptr, agg, out);
    } else {
        // fallback: round-1 atomic-scatter path (ws layout: deg + agg only)
        float* deg = (float*)d_ws;
        float* ag  = (float*)d_ws + N_NODES;
        k_init<<<(N_NODES + B - 1) / B, B, 0, stream>>>(deg, (int*)nullptr);
        k_degcnt<<<(N_EDGES + B - 1) / B, B, 0, stream>>>(dst, w, deg, (int*)nullptr);
        k_dinv_agg<<<(N_NODES + B - 1) / B, B, 0, stream>>>(x, deg, ag);
        k_scatter<<<((size_t)N_EDGES * 4 + B - 1) / B, B, 0, stream>>>(src, dst, w, deg, x, ag);
        k_mlp<<<N_NODES / 4, B, 0, stream>>>(ag, W1, b1, W2, b2, deg, out);
        k_scatter<<<((size_t)N_EDGES * 4 + B - 1) / B, B, 0, stream>>>(src, dst, w, deg, ag, out);
    }
}

// Round 3
// 588.670 us; speedup vs baseline: 2.7299x; 1.3300x over previous
//
#include <hip/hip_runtime.h>

#define N_NODES 100000
#define N_EDGES 3200000
#define N_PAD   100096
#define ELL_CAP 72
#define OVF_MAX 65536
#define FIXSCALE 16777216.0f      // 2^24
#define LOWMASK  ((1ULL << 40) - 1)
#define SCAN_CHUNK 2048
#define SCAN_BLOCKS ((N_NODES + SCAN_CHUNK - 1) / SCAN_CHUNK)

typedef unsigned long long ull;

// ===================== ELL fast path =====================

// zero packed[], extra[], ovf_cnt
__global__ __launch_bounds__(256) void k_zero(ull* __restrict__ packed,
                                              float4* __restrict__ extra4,
                                              int* __restrict__ ovf_cnt) {
    int i = blockIdx.x * blockDim.x + threadIdx.x;
    if (i < N_NODES * 4) extra4[i] = make_float4(0.f, 0.f, 0.f, 0.f);
    if (i < N_NODES) packed[i] = 0ULL;
    if (i == 0) *ovf_cnt = 0;
}

// one pass: packed[dst] += (1<<40)|fix(w); ell[dst*CAP + slot] = {src, w}
__global__ __launch_bounds__(256) void k_build(const int* __restrict__ src,
                                               const int* __restrict__ dst,
                                               const float* __restrict__ w,
                                               ull* __restrict__ packed,
                                               int2* __restrict__ ell,
                                               int* __restrict__ ovs,
                                               int* __restrict__ ovd,
                                               float* __restrict__ ovw,
                                               int* __restrict__ ovf_cnt) {
    int e = blockIdx.x * blockDim.x + threadIdx.x;
    if (e >= N_EDGES) return;
    int s = src[e], d = dst[e];
    float wv = w[e];
    ull inc = (1ULL << 40) | (ull)__float2uint_rn(wv * FIXSCALE);
    ull old = atomicAdd(&packed[d], inc);
    int pos = (int)(old >> 40);
    if (pos < ELL_CAP) {
        ell[(size_t)d * ELL_CAP + pos] = make_int2(s, __float_as_int(wv));
    } else {
        int oi = atomicAdd(ovf_cnt, 1);
        if (oi < OVF_MAX) { ovs[oi] = s; ovd[oi] = d; ovw[oi] = wv; }
    }
}

// dinv[i] = rsqrt(1 + fixdeg/2^24)
__global__ __launch_bounds__(256) void k_node(const ull* __restrict__ packed,
                                              float* __restrict__ dinv) {
    int i = blockIdx.x * blockDim.x + threadIdx.x;
    if (i >= N_NODES) return;
    float deg = 1.0f + (float)(packed[i] & LOWMASK) * (1.0f / FIXSCALE);
    dinv[i] = rsqrtf(deg);
}

// overflow edges -> atomicAdd(target[d*16+c], nrm * feat[s*16+c])
__global__ __launch_bounds__(256) void k_ovf(const int* __restrict__ ovs,
                                             const int* __restrict__ ovd,
                                             const float* __restrict__ ovw,
                                             const int* __restrict__ ovf_cnt,
                                             const float* __restrict__ dinv,
                                             const float* __restrict__ feat,
                                             float* __restrict__ target) {
    int n = *ovf_cnt; if (n > OVF_MAX) n = OVF_MAX;
    int total = n * 4;
    int stride = gridDim.x * blockDim.x;
    for (int t = blockIdx.x * blockDim.x + threadIdx.x; t < total; t += stride) {
        int e = t >> 2, c4 = (t & 3) * 4;
        int s = ovs[e], d = ovd[e];
        float nrm = dinv[s] * ovw[e] * dinv[d];
        float4 v = *(const float4*)(feat + (size_t)s * 16 + c4);
        float* o = target + (size_t)d * 16 + c4;
        atomicAdd(o + 0, nrm * v.x);
        atomicAdd(o + 1, nrm * v.y);
        atomicAdd(o + 2, nrm * v.z);
        atomicAdd(o + 3, nrm * v.w);
    }
}

// fused: layer-1 gather (ELL) + self term + extra + MLP -> h2, out init.
// one wave per node; 64 lanes = 4 edge-slots x 16 channels.
__global__ __launch_bounds__(256) void k_gather_mlp(const int2* __restrict__ ell,
                                                    const ull* __restrict__ packed,
                                                    const float* __restrict__ dinv,
                                                    const float* __restrict__ x,
                                                    const float* __restrict__ extra,
                                                    const float* __restrict__ W1,
                                                    const float* __restrict__ b1,
                                                    const float* __restrict__ W2,
                                                    const float* __restrict__ b2,
                                                    float* __restrict__ h2out,
                                                    float* __restrict__ out) {
    __shared__ float fvs[4][16];
    __shared__ float o1s[4][128];
    int wave = threadIdx.x >> 6, lane = threadIdx.x & 63;
    int node = blockIdx.x * 4 + wave;        // N_NODES % 4 == 0
    int c = lane & 15, eo = lane >> 4;
    int cnt = (int)(packed[node] >> 40);
    if (cnt > ELL_CAP) cnt = ELL_CAP;
    float di = dinv[node];
    const int2* row = ell + (size_t)node * ELL_CAP;
    float acc = 0.0f;
    for (int j = eo; j < cnt; j += 4) {
        int2 ed = row[j];
        float nrm = dinv[ed.x] * __int_as_float(ed.y) * di;
        acc = fmaf(nrm, x[(size_t)ed.x * 16 + c], acc);
    }
    acc += __shfl_xor(acc, 16, 64);
    acc += __shfl_xor(acc, 32, 64);
    // self-loop + overflow extras (identical across the 4 lanes sharing c)
    acc += di * di * x[(size_t)node * 16 + c] + extra[(size_t)node * 16 + c];
    if (lane < 16) fvs[wave][c] = acc;
    __syncthreads();
    float fv[16];
#pragma unroll
    for (int k = 0; k < 16; k++) fv[k] = fvs[wave][k];
    float a = b1[2 * lane], b = b1[2 * lane + 1];
#pragma unroll
    for (int k = 0; k < 16; k++) {
        float2 wv = *(const float2*)(W1 + k * 128 + 2 * lane);
        a = fmaf(fv[k], wv.x, a);
        b = fmaf(fv[k], wv.y, b);
    }
    o1s[wave][2 * lane + 0] = fmaxf(a, 0.0f);
    o1s[wave][2 * lane + 1] = fmaxf(b, 0.0f);
    __syncthreads();
    int g = lane >> 4;
    float p = 0.0f;
#pragma unroll
    for (int k = 0; k < 32; k++) {
        int kk = g * 32 + k;
        p = fmaf(o1s[wave][kk], W2[kk * 16 + c], p);
    }
    p += __shfl_down(p, 16, 64);
    p += __shfl_down(p, 32, 64);
    if (lane < 16) {
        h2out[(size_t)node * 16 + c] = p;
        out[(size_t)node * 16 + c] = di * di * p + b2[c];
    }
}

// layer-2 neighbor gather: out[node*16+c] += sum nrm*h2[src]
__global__ __launch_bounds__(256) void k_gather2(const int2* __restrict__ ell,
                                                 const ull* __restrict__ packed,
                                                 const float* __restrict__ dinv,
                                                 const float* __restrict__ h2,
                                                 float* __restrict__ out) {
    int wave = threadIdx.x >> 6, lane = threadIdx.x & 63;
    int node = blockIdx.x * 4 + wave;
    int c = lane & 15, eo = lane >> 4;
    int cnt = (int)(packed[node] >> 40);
    if (cnt > ELL_CAP) cnt = ELL_CAP;
    float di = dinv[node];
    const int2* row = ell + (size_t)node * ELL_CAP;
    float acc = 0.0f;
    for (int j = eo; j < cnt; j += 4) {
        int2 ed = row[j];
        float nrm = dinv[ed.x] * __int_as_float(ed.y) * di;
        acc = fmaf(nrm, h2[(size_t)ed.x * 16 + c], acc);
    }
    acc += __shfl_xor(acc, 16, 64);
    acc += __shfl_xor(acc, 32, 64);
    if (lane < 16) out[(size_t)node * 16 + c] += acc;
}

// ===================== CSR fallback (round-2) =====================

__global__ void k_init(float* __restrict__ deg, int* __restrict__ cnt) {
    int i = blockIdx.x * blockDim.x + threadIdx.x;
    if (i < N_NODES) { deg[i] = 1.0f; if (cnt) cnt[i] = 0; }
}

__global__ void k_degcnt(const int* __restrict__ dst, const float* __restrict__ w,
                         float* __restrict__ deg, int* __restrict__ cnt) {
    int e = blockIdx.x * blockDim.x + threadIdx.x;
    if (e < N_EDGES) {
        int d = dst[e];
        atomicAdd(&deg[d], w[e]);
        if (cnt) atomicAdd(&cnt[d], 1);
    }
}

__global__ void k_dinv_agg(const float* __restrict__ x, float* __restrict__ deg_dinv,
                           float* __restrict__ agg) {
    int i = blockIdx.x * blockDim.x + threadIdx.x;
    if (i >= N_NODES) return;
    float di = rsqrtf(deg_dinv[i]);
    deg_dinv[i] = di;
    float s = di * di;
    const float4* xr = (const float4*)(x + (size_t)i * 16);
    float4* ar = (float4*)(agg + (size_t)i * 16);
#pragma unroll
    for (int k = 0; k < 4; k++) {
        float4 v = xr[k];
        v.x *= s; v.y *= s; v.z *= s; v.w *= s;
        ar[k] = v;
    }
}

__global__ __launch_bounds__(256) void k_scan1(const int* __restrict__ cnt,
                                               int* __restrict__ rowptr,
                                               int* __restrict__ bsum) {
    __shared__ int ts[256];
    int tid = threadIdx.x;
    int base = blockIdx.x * SCAN_CHUNK + tid * 8;
    int v[8]; int s = 0;
#pragma unroll
    for (int k = 0; k < 8; k++) {
        int idx = base + k;
        v[k] = (idx < N_NODES) ? cnt[idx] : 0;
        s += v[k];
    }
    ts[tid] = s;
    __syncthreads();
    for (int off = 1; off < 256; off <<= 1) {
        int t = (tid >= off) ? ts[tid - off] : 0;
        __syncthreads();
        ts[tid] += t;
        __syncthreads();
    }
    int run = ts[tid] - s;
#pragma unroll
    for (int k = 0; k < 8; k++) {
        int idx = base + k;
        if (idx < N_NODES) rowptr[idx] = run;
        run += v[k];
    }
    if (tid == 255) bsum[blockIdx.x] = ts[255];
}

__global__ void k_scan2(int* __restrict__ bsum) {
    if (threadIdx.x == 0 && blockIdx.x == 0) {
        int run = 0;
        for (int g = 0; g < SCAN_BLOCKS; g++) { int t = bsum[g]; bsum[g] = run; run += t; }
    }
}

__global__ __launch_bounds__(256) void k_scan3(int* __restrict__ rowptr,
                                               const int* __restrict__ bsum) {
    int tid = threadIdx.x;
    int base = blockIdx.x * SCAN_CHUNK + tid * 8;
    int off = bsum[blockIdx.x];
#pragma unroll
    for (int k = 0; k < 8; k++) {
        int idx = base + k;
        if (idx < N_NODES) rowptr[idx] += off;
    }
    if (blockIdx.x == 0 && tid == 0) rowptr[N_NODES] = N_EDGES;
}

__global__ void k_fill(const int* __restrict__ src, const int* __restrict__ dst,
                       const float* __restrict__ w, const float* __restrict__ dinv,
                       const int* __restrict__ rowptr, int* __restrict__ cnt,
                       int2* __restrict__ perm) {
    int e = blockIdx.x * blockDim.x + threadIdx.x;
    if (e >= N_EDGES) return;
    int s = src[e], d = dst[e];
    float nrm = dinv[s] * w[e] * dinv[d];
    int r = atomicSub(&cnt[d], 1) - 1;
    int pos = rowptr[d] + r;
    perm[pos] = make_int2(s, __float_as_int(nrm));
}

__global__ __launch_bounds__(256) void k_gather(const int2* __restrict__ perm,
                                                const int* __restrict__ rowptr,
                                                const float* __restrict__ feat,
                                                float* __restrict__ out) {
    int wave = threadIdx.x >> 6, lane = threadIdx.x & 63;
    int node = blockIdx.x * 4 + wave;
    int c = lane & 15, eo = lane >> 4;
    int beg = rowptr[node], end = rowptr[node + 1];
    float acc = 0.0f;
    for (int j = beg + eo; j < end; j += 4) {
        int2 ed = perm[j];
        acc = fmaf(__int_as_float(ed.y), feat[(size_t)ed.x * 16 + c], acc);
    }
    acc += __shfl_xor(acc, 16, 64);
    acc += __shfl_xor(acc, 32, 64);
    if (lane < 16) out[(size_t)node * 16 + c] += acc;
}

__global__ __launch_bounds__(256) void k_mlp(float* __restrict__ agg,
                                             const float* __restrict__ W1,
                                             const float* __restrict__ b1,
                                             const float* __restrict__ W2,
                                             const float* __restrict__ b2,
                                             const float* __restrict__ dinv,
                                             float* __restrict__ out) {
    __shared__ float o1s[4][128];
    int wave = threadIdx.x >> 6;
    int lane = threadIdx.x & 63;
    int node = blockIdx.x * 4 + wave;
    const float* f = agg + (size_t)node * 16;
    float fv[16];
#pragma unroll
    for (int k = 0; k < 4; k++) {
        float4 v = ((const float4*)f)[k];
        fv[4 * k + 0] = v.x; fv[4 * k + 1] = v.y; fv[4 * k + 2] = v.z; fv[4 * k + 3] = v.w;
    }
    float a = b1[2 * lane], b = b1[2 * lane + 1];
#pragma unroll
    for (int k = 0; k < 16; k++) {
        float2 wv = *(const float2*)(W1 + k * 128 + 2 * lane);
        a = fmaf(fv[k], wv.x, a);
        b = fmaf(fv[k], wv.y, b);
    }
    o1s[wave][2 * lane + 0] = fmaxf(a, 0.0f);
    o1s[wave][2 * lane + 1] = fmaxf(b, 0.0f);
    __syncthreads();
    int c = lane & 15, g = lane >> 4;
    float p = 0.0f;
#pragma unroll
    for (int k = 0; k < 32; k++) {
        int kk = g * 32 + k;
        p = fmaf(o1s[wave][kk], W2[kk * 16 + c], p);
    }
    p += __shfl_down(p, 16, 64);
    p += __shfl_down(p, 32, 64);
    __syncthreads();
    if (lane < 16) {
        float h2v = p;
        agg[(size_t)node * 16 + c] = h2v;
        float di = dinv[node];
        out[(size_t)node * 16 + c] = di * di * h2v + b2[c];
    }
}

__global__ void k_scatter(const int* __restrict__ src, const int* __restrict__ dst,
                          const float* __restrict__ w, const float* __restrict__ dinv,
                          const float* __restrict__ feat, float* __restrict__ out) {
    int t = blockIdx.x * blockDim.x + threadIdx.x;
    int e = t >> 2;
    int c4 = (t & 3) * 4;
    if (e >= N_EDGES) return;
    int s = src[e], d = dst[e];
    float nrm = dinv[s] * w[e] * dinv[d];
    float4 v = *(const float4*)(feat + (size_t)s * 16 + c4);
    float* o = out + (size_t)d * 16 + c4;
    atomicAdd(o + 0, nrm * v.x);
    atomicAdd(o + 1, nrm * v.y);
    atomicAdd(o + 2, nrm * v.z);
    atomicAdd(o + 3, nrm * v.w);
}

// ===================== launch =====================

extern "C" void kernel_launch(void* const* d_in, const int* in_sizes, int n_in,
                              void* d_out, int out_size, void* d_ws, size_t ws_size,
                              hipStream_t stream) {
    const float* x  = (const float*)d_in[0];
    const int*   ei = (const int*)d_in[1];
    const float* w  = (const float*)d_in[2];
    const float* W1 = (const float*)d_in[3];
    const float* b1 = (const float*)d_in[4];
    const float* W2 = (const float*)d_in[5];
    const float* b2 = (const float*)d_in[6];
    float* out = (float*)d_out;

    const int* src = ei;
    const int* dst = ei + N_EDGES;
    const int B = 256;

    // ---- ELL workspace layout ----
    char* p = (char*)d_ws;
    ull*   packed = (ull*)p;                 p += (size_t)N_PAD * 8;
    int2*  ell    = (int2*)p;                p += (size_t)N_NODES * ELL_CAP * 8;
    float* dinv   = (float*)p;               p += (size_t)N_PAD * 4;
    float* extra  = (float*)p;               p += (size_t)N_NODES * 16 * 4;
    float* h2     = (float*)p;               p += (size_t)N_NODES * 16 * 4;
    int*   ovs    = (int*)p;                 p += (size_t)OVF_MAX * 4;
    int*   ovd    = (int*)p;                 p += (size_t)OVF_MAX * 4;
    float* ovw    = (float*)p;               p += (size_t)OVF_MAX * 4;
    int*   ovf_cnt = (int*)p;                p += 16;
    const size_t WS_ELL = (size_t)(p - (char*)d_ws);

    if (ws_size >= WS_ELL) {
        k_zero<<<(N_NODES * 4 + B - 1) / B, B, 0, stream>>>(packed, (float4*)extra, ovf_cnt);
        k_build<<<N_EDGES / B, B, 0, stream>>>(src, dst, w, packed, ell, ovs, ovd, ovw, ovf_cnt);
        k_node<<<(N_NODES + B - 1) / B, B, 0, stream>>>(packed, dinv);
        k_ovf<<<64, B, 0, stream>>>(ovs, ovd, ovw, ovf_cnt, dinv, x, extra);
        k_gather_mlp<<<N_NODES / 4, B, 0, stream>>>(ell, packed, dinv, x, extra,
                                                    W1, b1, W2, b2, h2, out);
        k_gather2<<<N_NODES / 4, B, 0, stream>>>(ell, packed, dinv, h2, out);
        k_ovf<<<64, B, 0, stream>>>(ovs, ovd, ovw, ovf_cnt, dinv, h2, out);
        return;
    }

    // ---- CSR fallback (round-2 path) ----
    float* deg_dinv = (float*)d_ws;
    int*   cnt      = (int*)(deg_dinv + N_PAD);
    int*   rowptr   = cnt + N_PAD;
    int*   bsum     = rowptr + N_PAD;
    float* agg      = (float*)(bsum + 64);
    int2*  perm     = (int2*)(agg + (size_t)N_NODES * 16);
    const size_t WS_CSR = ((size_t)N_PAD * 3 + 64 + (size_t)N_NODES * 16) * 4
                          + (size_t)N_EDGES * 8;

    if (ws_size >= WS_CSR) {
        k_init<<<(N_NODES + B - 1) / B, B, 0, stream>>>(deg_dinv, cnt);
        k_degcnt<<<(N_EDGES + B - 1) / B, B, 0, stream>>>(dst, w, deg_dinv, cnt);
        k_dinv_agg<<<(N_NODES + B - 1) / B, B, 0, stream>>>(x, deg_dinv, agg);
        k_scan1<<<SCAN_BLOCKS, 256, 0, stream>>>(cnt, rowptr, bsum);
        k_scan2<<<1, 64, 0, stream>>>(bsum);
        k_scan3<<<SCAN_BLOCKS, 256, 0, stream>>>(rowptr, bsum);
        k_fill<<<(N_EDGES + B - 1) / B, B, 0, stream>>>(src, dst, w, deg_dinv,
                                                        rowptr, cnt, perm);
        k_gather<<<N_NODES / 4, B, 0, stream>>>(perm, rowptr, x, agg);
        k_mlp<<<N_NODES / 4, B, 0, stream>>>(agg, W1, b1, W2, b2, deg_dinv, out);
        k_gather<<<N_NODES / 4, B, 0, stream>>>(perm, rowptr, agg, out);
    } else {
        float* deg = (float*)d_ws;
        float* ag  = (float*)d_ws + N_NODES;
        k_init<<<(N_NODES + B - 1) / B, B, 0, stream>>>(deg, (int*)nullptr);
        k_degcnt<<<(N_EDGES + B - 1) / B, B, 0, stream>>>(dst, w, deg, (int*)nullptr);
        k_dinv_agg<<<(N_NODES + B - 1) / B, B, 0, stream>>>(x, deg, ag);
        k_scatter<<<((size_t)N_EDGES * 4 + B - 1) / B, B, 0, stream>>>(src, dst, w, deg, x, ag);
        k_mlp<<<N_NODES / 4, B, 0, stream>>>(ag, W1, b1, W2, b2, deg, out);
        k_scatter<<<((size_t)N_EDGES * 4 + B - 1) / B, B, 0, stream>>>(src, dst, w, deg, ag, out);
    }
}

// Round 4
// 522.260 us; speedup vs baseline: 3.0771x; 1.1272x over previous
//
#include <hip/hip_runtime.h>

#define N_NODES 100000
#define N_EDGES 3200000
#define N_PAD   100096
#define ELL_CAP 64
#define OVF_MAX 65536
#define FIXSCALE 16777216.0f      // 2^24
#define WQSCALE  32767.0f         // 15-bit weight quant
#define LOWMASK  ((1ULL << 40) - 1)
#define SCAN_CHUNK 2048
#define SCAN_BLOCKS ((N_NODES + SCAN_CHUNK - 1) / SCAN_CHUNK)

typedef unsigned long long ull;

// ===================== ELL fast path =====================

// zero packed[], extra[], ovf_cnt
__global__ __launch_bounds__(256) void k_zero(ull* __restrict__ packed,
                                              float4* __restrict__ extra4,
                                              int* __restrict__ ovf_cnt) {
    int i = blockIdx.x * blockDim.x + threadIdx.x;
    if (i < N_NODES * 4) extra4[i] = make_float4(0.f, 0.f, 0.f, 0.f);
    if (i < N_NODES) packed[i] = 0ULL;
    if (i == 0) *ovf_cnt = 0;
}

// one pass, 8 edges/thread: packed[dst] += (1<<40)|fix(w);
// ell[dst*CAP + slot] = (wq<<17)|src   (4B entries)
__global__ __launch_bounds__(256) void k_build(const int* __restrict__ src,
                                               const int* __restrict__ dst,
                                               const float* __restrict__ w,
                                               ull* __restrict__ packed,
                                               unsigned* __restrict__ ell,
                                               int* __restrict__ ovs,
                                               int* __restrict__ ovd,
                                               float* __restrict__ ovw,
                                               int* __restrict__ ovf_cnt) {
    int t = blockIdx.x * blockDim.x + threadIdx.x;
    const int T = gridDim.x * blockDim.x;
    int s8[8], d8[8];
    float w8[8];
    bool ok[8];
#pragma unroll
    for (int k = 0; k < 8; k++) {
        int e = t + k * T;
        ok[k] = (e < N_EDGES);
        if (ok[k]) { s8[k] = src[e]; d8[k] = dst[e]; w8[k] = w[e]; }
    }
    ull old8[8];
#pragma unroll
    for (int k = 0; k < 8; k++) {
        if (ok[k]) {
            ull inc = (1ULL << 40) | (ull)__float2uint_rn(w8[k] * FIXSCALE);
            old8[k] = atomicAdd(&packed[d8[k]], inc);
        }
    }
#pragma unroll
    for (int k = 0; k < 8; k++) {
        if (ok[k]) {
            int pos = (int)(old8[k] >> 40);
            unsigned wq = __float2uint_rn(w8[k] * WQSCALE);
            unsigned entry = (wq << 17) | (unsigned)s8[k];
            if (pos < ELL_CAP) {
                ell[(size_t)d8[k] * ELL_CAP + pos] = entry;
            } else {
                int oi = atomicAdd(ovf_cnt, 1);
                if (oi < OVF_MAX) { ovs[oi] = s8[k]; ovd[oi] = d8[k]; ovw[oi] = w8[k]; }
            }
        }
    }
}

// dinv[i] = rsqrt(1 + fixdeg/2^24)
__global__ __launch_bounds__(256) void k_node(const ull* __restrict__ packed,
                                              float* __restrict__ dinv) {
    int i = blockIdx.x * blockDim.x + threadIdx.x;
    if (i >= N_NODES) return;
    float deg = 1.0f + (float)(packed[i] & LOWMASK) * (1.0f / FIXSCALE);
    dinv[i] = rsqrtf(deg);
}

// overflow edges -> atomicAdd(target[d*16+c], nrm * feat[s*16+c])
__global__ __launch_bounds__(256) void k_ovf(const int* __restrict__ ovs,
                                             const int* __restrict__ ovd,
                                             const float* __restrict__ ovw,
                                             const int* __restrict__ ovf_cnt,
                                             const float* __restrict__ dinv,
                                             const float* __restrict__ feat,
                                             float* __restrict__ target) {
    int n = *ovf_cnt; if (n > OVF_MAX) n = OVF_MAX;
    int total = n * 4;
    int stride = gridDim.x * blockDim.x;
    for (int t = blockIdx.x * blockDim.x + threadIdx.x; t < total; t += stride) {
        int e = t >> 2, c4 = (t & 3) * 4;
        int s = ovs[e], d = ovd[e];
        float nrm = dinv[s] * ovw[e] * dinv[d];
        float4 v = *(const float4*)(feat + (size_t)s * 16 + c4);
        float* o = target + (size_t)d * 16 + c4;
        atomicAdd(o + 0, nrm * v.x);
        atomicAdd(o + 1, nrm * v.y);
        atomicAdd(o + 2, nrm * v.z);
        atomicAdd(o + 3, nrm * v.w);
    }
}

// fused: layer-1 gather (ELL) + self term + extra + MLP -> h2, out init.
__global__ __launch_bounds__(256) void k_gather_mlp(const unsigned* __restrict__ ell,
                                                    const ull* __restrict__ packed,
                                                    const float* __restrict__ dinv,
                                                    const float* __restrict__ x,
                                                    const float* __restrict__ extra,
                                                    const float* __restrict__ W1,
                                                    const float* __restrict__ b1,
                                                    const float* __restrict__ W2,
                                                    const float* __restrict__ b2,
                                                    float* __restrict__ h2out,
                                                    float* __restrict__ out) {
    __shared__ float fvs[4][16];
    __shared__ float o1s[4][128];
    int wave = threadIdx.x >> 6, lane = threadIdx.x & 63;
    int node = blockIdx.x * 4 + wave;        // N_NODES % 4 == 0
    int c = lane & 15, eo = lane >> 4;
    int cnt = (int)(packed[node] >> 40);
    if (cnt > ELL_CAP) cnt = ELL_CAP;
    float di = dinv[node];
    const unsigned* row = ell + (size_t)node * ELL_CAP;
    float acc = 0.0f;
    for (int j = eo; j < cnt; j += 4) {
        unsigned ed = row[j];
        int s = ed & 0x1FFFF;
        float wv = (float)(ed >> 17) * (1.0f / WQSCALE);
        float nrm = dinv[s] * wv * di;
        acc = fmaf(nrm, x[(size_t)s * 16 + c], acc);
    }
    acc += __shfl_xor(acc, 16, 64);
    acc += __shfl_xor(acc, 32, 64);
    acc += di * di * x[(size_t)node * 16 + c] + extra[(size_t)node * 16 + c];
    if (lane < 16) fvs[wave][c] = acc;
    __syncthreads();
    float fv[16];
#pragma unroll
    for (int k = 0; k < 16; k++) fv[k] = fvs[wave][k];
    float a = b1[2 * lane], b = b1[2 * lane + 1];
#pragma unroll
    for (int k = 0; k < 16; k++) {
        float2 wv = *(const float2*)(W1 + k * 128 + 2 * lane);
        a = fmaf(fv[k], wv.x, a);
        b = fmaf(fv[k], wv.y, b);
    }
    o1s[wave][2 * lane + 0] = fmaxf(a, 0.0f);
    o1s[wave][2 * lane + 1] = fmaxf(b, 0.0f);
    __syncthreads();
    int g = lane >> 4;
    float p = 0.0f;
#pragma unroll
    for (int k = 0; k < 32; k++) {
        int kk = g * 32 + k;
        p = fmaf(o1s[wave][kk], W2[kk * 16 + c], p);
    }
    p += __shfl_down(p, 16, 64);
    p += __shfl_down(p, 32, 64);
    if (lane < 16) {
        h2out[(size_t)node * 16 + c] = p;
        out[(size_t)node * 16 + c] = di * di * p + b2[c];
    }
}

// layer-2 neighbor gather: out[node*16+c] += sum nrm*h2[src]
__global__ __launch_bounds__(256) void k_gather2(const unsigned* __restrict__ ell,
                                                 const ull* __restrict__ packed,
                                                 const float* __restrict__ dinv,
                                                 const float* __restrict__ h2,
                                                 float* __restrict__ out) {
    int wave = threadIdx.x >> 6, lane = threadIdx.x & 63;
    int node = blockIdx.x * 4 + wave;
    int c = lane & 15, eo = lane >> 4;
    int cnt = (int)(packed[node] >> 40);
    if (cnt > ELL_CAP) cnt = ELL_CAP;
    float di = dinv[node];
    const unsigned* row = ell + (size_t)node * ELL_CAP;
    float acc = 0.0f;
    for (int j = eo; j < cnt; j += 4) {
        unsigned ed = row[j];
        int s = ed & 0x1FFFF;
        float wv = (float)(ed >> 17) * (1.0f / WQSCALE);
        float nrm = dinv[s] * wv * di;
        acc = fmaf(nrm, h2[(size_t)s * 16 + c], acc);
    }
    acc += __shfl_xor(acc, 16, 64);
    acc += __shfl_xor(acc, 32, 64);
    if (lane < 16) out[(size_t)node * 16 + c] += acc;
}

// ===================== CSR fallback (round-2) =====================

__global__ void k_init(float* __restrict__ deg, int* __restrict__ cnt) {
    int i = blockIdx.x * blockDim.x + threadIdx.x;
    if (i < N_NODES) { deg[i] = 1.0f; if (cnt) cnt[i] = 0; }
}

__global__ void k_degcnt(const int* __restrict__ dst, const float* __restrict__ w,
                         float* __restrict__ deg, int* __restrict__ cnt) {
    int e = blockIdx.x * blockDim.x + threadIdx.x;
    if (e < N_EDGES) {
        int d = dst[e];
        atomicAdd(&deg[d], w[e]);
        if (cnt) atomicAdd(&cnt[d], 1);
    }
}

__global__ void k_dinv_agg(const float* __restrict__ x, float* __restrict__ deg_dinv,
                           float* __restrict__ agg) {
    int i = blockIdx.x * blockDim.x + threadIdx.x;
    if (i >= N_NODES) return;
    float di = rsqrtf(deg_dinv[i]);
    deg_dinv[i] = di;
    float s = di * di;
    const float4* xr = (const float4*)(x + (size_t)i * 16);
    float4* ar = (float4*)(agg + (size_t)i * 16);
#pragma unroll
    for (int k = 0; k < 4; k++) {
        float4 v = xr[k];
        v.x *= s; v.y *= s; v.z *= s; v.w *= s;
        ar[k] = v;
    }
}

__global__ __launch_bounds__(256) void k_scan1(const int* __restrict__ cnt,
                                               int* __restrict__ rowptr,
                                               int* __restrict__ bsum) {
    __shared__ int ts[256];
    int tid = threadIdx.x;
    int base = blockIdx.x * SCAN_CHUNK + tid * 8;
    int v[8]; int s = 0;
#pragma unroll
    for (int k = 0; k < 8; k++) {
        int idx = base + k;
        v[k] = (idx < N_NODES) ? cnt[idx] : 0;
        s += v[k];
    }
    ts[tid] = s;
    __syncthreads();
    for (int off = 1; off < 256; off <<= 1) {
        int t = (tid >= off) ? ts[tid - off] : 0;
        __syncthreads();
        ts[tid] += t;
        __syncthreads();
    }
    int run = ts[tid] - s;
#pragma unroll
    for (int k = 0; k < 8; k++) {
        int idx = base + k;
        if (idx < N_NODES) rowptr[idx] = run;
        run += v[k];
    }
    if (tid == 255) bsum[blockIdx.x] = ts[255];
}

__global__ void k_scan2(int* __restrict__ bsum) {
    if (threadIdx.x == 0 && blockIdx.x == 0) {
        int run = 0;
        for (int g = 0; g < SCAN_BLOCKS; g++) { int t = bsum[g]; bsum[g] = run; run += t; }
    }
}

__global__ __launch_bounds__(256) void k_scan3(int* __restrict__ rowptr,
                                               const int* __restrict__ bsum) {
    int tid = threadIdx.x;
    int base = blockIdx.x * SCAN_CHUNK + tid * 8;
    int off = bsum[blockIdx.x];
#pragma unroll
    for (int k = 0; k < 8; k++) {
        int idx = base + k;
        if (idx < N_NODES) rowptr[idx] += off;
    }
    if (blockIdx.x == 0 && tid == 0) rowptr[N_NODES] = N_EDGES;
}

__global__ void k_fill(const int* __restrict__ src, const int* __restrict__ dst,
                       const float* __restrict__ w, const float* __restrict__ dinv,
                       const int* __restrict__ rowptr, int* __restrict__ cnt,
                       int2* __restrict__ perm) {
    int e = blockIdx.x * blockDim.x + threadIdx.x;
    if (e >= N_EDGES) return;
    int s = src[e], d = dst[e];
    float nrm = dinv[s] * w[e] * dinv[d];
    int r = atomicSub(&cnt[d], 1) - 1;
    int pos = rowptr[d] + r;
    perm[pos] = make_int2(s, __float_as_int(nrm));
}

__global__ __launch_bounds__(256) void k_gather(const int2* __restrict__ perm,
                                                const int* __restrict__ rowptr,
                                                const float* __restrict__ feat,
                                                float* __restrict__ out) {
    int wave = threadIdx.x >> 6, lane = threadIdx.x & 63;
    int node = blockIdx.x * 4 + wave;
    int c = lane & 15, eo = lane >> 4;
    int beg = rowptr[node], end = rowptr[node + 1];
    float acc = 0.0f;
    for (int j = beg + eo; j < end; j += 4) {
        int2 ed = perm[j];
        acc = fmaf(__int_as_float(ed.y), feat[(size_t)ed.x * 16 + c], acc);
    }
    acc += __shfl_xor(acc, 16, 64);
    acc += __shfl_xor(acc, 32, 64);
    if (lane < 16) out[(size_t)node * 16 + c] += acc;
}

__global__ __launch_bounds__(256) void k_mlp(float* __restrict__ agg,
                                             const float* __restrict__ W1,
                                             const float* __restrict__ b1,
                                             const float* __restrict__ W2,
                                             const float* __restrict__ b2,
                                             const float* __restrict__ dinv,
                                             float* __restrict__ out) {
    __shared__ float o1s[4][128];
    int wave = threadIdx.x >> 6;
    int lane = threadIdx.x & 63;
    int node = blockIdx.x * 4 + wave;
    const float* f = agg + (size_t)node * 16;
    float fv[16];
#pragma unroll
    for (int k = 0; k < 4; k++) {
        float4 v = ((const float4*)f)[k];
        fv[4 * k + 0] = v.x; fv[4 * k + 1] = v.y; fv[4 * k + 2] = v.z; fv[4 * k + 3] = v.w;
    }
    float a = b1[2 * lane], b = b1[2 * lane + 1];
#pragma unroll
    for (int k = 0; k < 16; k++) {
        float2 wv = *(const float2*)(W1 + k * 128 + 2 * lane);
        a = fmaf(fv[k], wv.x, a);
        b = fmaf(fv[k], wv.y, b);
    }
    o1s[wave][2 * lane + 0] = fmaxf(a, 0.0f);
    o1s[wave][2 * lane + 1] = fmaxf(b, 0.0f);
    __syncthreads();
    int c = lane & 15, g = lane >> 4;
    float p = 0.0f;
#pragma unroll
    for (int k = 0; k < 32; k++) {
        int kk = g * 32 + k;
        p = fmaf(o1s[wave][kk], W2[kk * 16 + c], p);
    }
    p += __shfl_down(p, 16, 64);
    p += __shfl_down(p, 32, 64);
    __syncthreads();
    if (lane < 16) {
        float h2v = p;
        agg[(size_t)node * 16 + c] = h2v;
        float di = dinv[node];
        out[(size_t)node * 16 + c] = di * di * h2v + b2[c];
    }
}

__global__ void k_scatter(const int* __restrict__ src, const int* __restrict__ dst,
                          const float* __restrict__ w, const float* __restrict__ dinv,
                          const float* __restrict__ feat, float* __restrict__ out) {
    int t = blockIdx.x * blockDim.x + threadIdx.x;
    int e = t >> 2;
    int c4 = (t & 3) * 4;
    if (e >= N_EDGES) return;
    int s = src[e], d = dst[e];
    float nrm = dinv[s] * w[e] * dinv[d];
    float4 v = *(const float4*)(feat + (size_t)s * 16 + c4);
    float* o = out + (size_t)d * 16 + c4;
    atomicAdd(o + 0, nrm * v.x);
    atomicAdd(o + 1, nrm * v.y);
    atomicAdd(o + 2, nrm * v.z);
    atomicAdd(o + 3, nrm * v.w);
}

// ===================== launch =====================

extern "C" void kernel_launch(void* const* d_in, const int* in_sizes, int n_in,
                              void* d_out, int out_size, void* d_ws, size_t ws_size,
                              hipStream_t stream) {
    const float* x  = (const float*)d_in[0];
    const int*   ei = (const int*)d_in[1];
    const float* w  = (const float*)d_in[2];
    const float* W1 = (const float*)d_in[3];
    const float* b1 = (const float*)d_in[4];
    const float* W2 = (const float*)d_in[5];
    const float* b2 = (const float*)d_in[6];
    float* out = (float*)d_out;

    const int* src = ei;
    const int* dst = ei + N_EDGES;
    const int B = 256;

    // ---- ELL workspace layout (all 16B-aligned offsets) ----
    char* p = (char*)d_ws;
    ull*      packed = (ull*)p;            p += (size_t)N_PAD * 8;
    unsigned* ell    = (unsigned*)p;       p += (size_t)N_NODES * ELL_CAP * 4;
    float*    dinv   = (float*)p;          p += (size_t)N_PAD * 4;
    float*    extra  = (float*)p;          p += (size_t)N_NODES * 16 * 4;
    float*    h2     = (float*)p;          p += (size_t)N_NODES * 16 * 4;
    int*      ovs    = (int*)p;            p += (size_t)OVF_MAX * 4;
    int*      ovd    = (int*)p;            p += (size_t)OVF_MAX * 4;
    float*    ovw    = (float*)p;          p += (size_t)OVF_MAX * 4;
    int*      ovf_cnt = (int*)p;           p += 16;
    const size_t WS_ELL = (size_t)(p - (char*)d_ws);

    if (ws_size >= WS_ELL) {
        const int buildB = (N_EDGES + 2048 - 1) / 2048;   // 8 edges/thread
        k_zero<<<(N_NODES * 4 + B - 1) / B, B, 0, stream>>>(packed, (float4*)extra, ovf_cnt);
        k_build<<<buildB, B, 0, stream>>>(src, dst, w, packed, ell, ovs, ovd, ovw, ovf_cnt);
        k_node<<<(N_NODES + B - 1) / B, B, 0, stream>>>(packed, dinv);
        k_ovf<<<64, B, 0, stream>>>(ovs, ovd, ovw, ovf_cnt, dinv, x, extra);
        k_gather_mlp<<<N_NODES / 4, B, 0, stream>>>(ell, packed, dinv, x, extra,
                                                    W1, b1, W2, b2, h2, out);
        k_gather2<<<N_NODES / 4, B, 0, stream>>>(ell, packed, dinv, h2, out);
        k_ovf<<<64, B, 0, stream>>>(ovs, ovd, ovw, ovf_cnt, dinv, h2, out);
        return;
    }

    // ---- CSR fallback (round-2 path) ----
    float* deg_dinv = (float*)d_ws;
    int*   cnt      = (int*)(deg_dinv + N_PAD);
    int*   rowptr   = cnt + N_PAD;
    int*   bsum     = rowptr + N_PAD;
    float* agg      = (float*)(bsum + 64);
    int2*  perm     = (int2*)(agg + (size_t)N_NODES * 16);
    const size_t WS_CSR = ((size_t)N_PAD * 3 + 64 + (size_t)N_NODES * 16) * 4
                          + (size_t)N_EDGES * 8;

    if (ws_size >= WS_CSR) {
        k_init<<<(N_NODES + B - 1) / B, B, 0, stream>>>(deg_dinv, cnt);
        k_degcnt<<<(N_EDGES + B - 1) / B, B, 0, stream>>>(dst, w, deg_dinv, cnt);
        k_dinv_agg<<<(N_NODES + B - 1) / B, B, 0, stream>>>(x, deg_dinv, agg);
        k_scan1<<<SCAN_BLOCKS, 256, 0, stream>>>(cnt, rowptr, bsum);
        k_scan2<<<1, 64, 0, stream>>>(bsum);
        k_scan3<<<SCAN_BLOCKS, 256, 0, stream>>>(rowptr, bsum);
        k_fill<<<(N_EDGES + B - 1) / B, B, 0, stream>>>(src, dst, w, deg_dinv,
                                                        rowptr, cnt, perm);
        k_gather<<<N_NODES / 4, B, 0, stream>>>(perm, rowptr, x, agg);
        k_mlp<<<N_NODES / 4, B, 0, stream>>>(agg, W1, b1, W2, b2, deg_dinv, out);
        k_gather<<<N_NODES / 4, B, 0, stream>>>(perm, rowptr, agg, out);
    } else {
        float* deg = (float*)d_ws;
        float* ag  = (float*)d_ws + N_NODES;
        k_init<<<(N_NODES + B - 1) / B, B, 0, stream>>>(deg, (int*)nullptr);
        k_degcnt<<<(N_EDGES + B - 1) / B, B, 0, stream>>>(dst, w, deg, (int*)nullptr);
        k_dinv_agg<<<(N_NODES + B - 1) / B, B, 0, stream>>>(x, deg, ag);
        k_scatter<<<((size_t)N_EDGES * 4 + B - 1) / B, B, 0, stream>>>(src, dst, w, deg, x, ag);
        k_mlp<<<N_NODES / 4, B, 0, stream>>>(ag, W1, b1, W2, b2, deg, out);
        k_scatter<<<((size_t)N_EDGES * 4 + B - 1) / B, B, 0, stream>>>(src, dst, w, deg, ag, out);
    }
}

// Round 5
// 496.254 us; speedup vs baseline: 3.2383x; 1.0524x over previous
//
#include <hip/hip_runtime.h>

#define N_NODES 100000
#define N_EDGES 3200000
#define N_PAD   100096
#define ELL_CAP 64
#define OVF_MAX 65536
#define XCDS    8
#define NODES_PER_XCD (N_NODES / XCDS)     // 12500
#define FIXSCALE 16777216.0f               // 2^24
#define WQSCALE  32767.0f                  // 15-bit weight quant
#define LOWMASK  ((1ULL << 40) - 1)
#define SCAN_CHUNK 2048
#define SCAN_BLOCKS ((N_NODES + SCAN_CHUNK - 1) / SCAN_CHUNK)

typedef unsigned long long ull;

// ===================== ELL fast path =====================

// zero packed[], extra[], ovf_cnt
__global__ __launch_bounds__(256) void k_zero(ull* __restrict__ packed,
                                              float4* __restrict__ extra4,
                                              int* __restrict__ ovf_cnt) {
    int i = blockIdx.x * blockDim.x + threadIdx.x;
    if (i < N_NODES * 4) extra4[i] = make_float4(0.f, 0.f, 0.f, 0.f);
    if (i < N_NODES) packed[i] = 0ULL;
    if (i == 0) *ovf_cnt = 0;
}

// XCD-partitioned build: block b handles XCD (b&7)'s dst range only.
// packed[dst] += (1<<40)|fix(w); ell[dst*CAP+slot] = (wq<<17)|src (4B entries)
__global__ __launch_bounds__(256) void k_build(const int* __restrict__ src,
                                               const int* __restrict__ dst,
                                               const float* __restrict__ w,
                                               ull* __restrict__ packed,
                                               unsigned* __restrict__ ell,
                                               int* __restrict__ ovs,
                                               int* __restrict__ ovd,
                                               float* __restrict__ ovw,
                                               int* __restrict__ ovf_cnt) {
    int xcd = blockIdx.x & 7;
    int chunk = blockIdx.x >> 3;
    int t = chunk * blockDim.x + threadIdx.x;
    const int T = (gridDim.x >> 3) * blockDim.x;
    const int lo = xcd * NODES_PER_XCD;
    const int hi = lo + NODES_PER_XCD;

    int s8[8], d8[8];
    float w8[8];
    bool ok[8];
#pragma unroll
    for (int k = 0; k < 8; k++) {
        int e = t + k * T;
        bool in = (e < N_EDGES);
        int d = in ? dst[e] : 0;
        s8[k] = in ? src[e] : 0;
        w8[k] = in ? w[e] : 0.0f;
        d8[k] = d;
        ok[k] = in && (d >= lo) && (d < hi);
    }
    ull old8[8];
#pragma unroll
    for (int k = 0; k < 8; k++) {
        if (ok[k]) {
            ull inc = (1ULL << 40) | (ull)__float2uint_rn(w8[k] * FIXSCALE);
            old8[k] = atomicAdd(&packed[d8[k]], inc);
        }
    }
#pragma unroll
    for (int k = 0; k < 8; k++) {
        if (ok[k]) {
            int pos = (int)(old8[k] >> 40);
            unsigned wq = __float2uint_rn(w8[k] * WQSCALE);
            unsigned entry = (wq << 17) | (unsigned)s8[k];
            if (pos < ELL_CAP) {
                ell[(size_t)d8[k] * ELL_CAP + pos] = entry;
            } else {
                int oi = atomicAdd(ovf_cnt, 1);
                if (oi < OVF_MAX) { ovs[oi] = s8[k]; ovd[oi] = d8[k]; ovw[oi] = w8[k]; }
            }
        }
    }
}

// dinv[i] = rsqrt(1 + fixdeg/2^24)
__global__ __launch_bounds__(256) void k_node(const ull* __restrict__ packed,
                                              float* __restrict__ dinv) {
    int i = blockIdx.x * blockDim.x + threadIdx.x;
    if (i >= N_NODES) return;
    float deg = 1.0f + (float)(packed[i] & LOWMASK) * (1.0f / FIXSCALE);
    dinv[i] = rsqrtf(deg);
}

// overflow edges -> atomicAdd(target[d*16+c], nrm * feat[s*16+c])
__global__ __launch_bounds__(256) void k_ovf(const int* __restrict__ ovs,
                                             const int* __restrict__ ovd,
                                             const float* __restrict__ ovw,
                                             const int* __restrict__ ovf_cnt,
                                             const float* __restrict__ dinv,
                                             const float* __restrict__ feat,
                                             float* __restrict__ target) {
    int n = *ovf_cnt; if (n > OVF_MAX) n = OVF_MAX;
    int total = n * 4;
    int stride = gridDim.x * blockDim.x;
    for (int t = blockIdx.x * blockDim.x + threadIdx.x; t < total; t += stride) {
        int e = t >> 2, c4 = (t & 3) * 4;
        int s = ovs[e], d = ovd[e];
        float nrm = dinv[s] * ovw[e] * dinv[d];
        float4 v = *(const float4*)(feat + (size_t)s * 16 + c4);
        float* o = target + (size_t)d * 16 + c4;
        atomicAdd(o + 0, nrm * v.x);
        atomicAdd(o + 1, nrm * v.y);
        atomicAdd(o + 2, nrm * v.z);
        atomicAdd(o + 3, nrm * v.w);
    }
}

// fused: layer-1 gather (ELL) + self term + extra(only if overflowed) + MLP.
// XCD-aligned node swizzle: block b -> nodes in XCD (b&7)'s range.
__global__ __launch_bounds__(256) void k_gather_mlp(const unsigned* __restrict__ ell,
                                                    const ull* __restrict__ packed,
                                                    const float* __restrict__ dinv,
                                                    const float* __restrict__ x,
                                                    const float* __restrict__ extra,
                                                    const float* __restrict__ W1,
                                                    const float* __restrict__ b1,
                                                    const float* __restrict__ W2,
                                                    const float* __restrict__ b2,
                                                    float* __restrict__ h2out,
                                                    float* __restrict__ out) {
    __shared__ float fvs[4][16];
    __shared__ float o1s[4][128];
    int wave = threadIdx.x >> 6, lane = threadIdx.x & 63;
    int node = (blockIdx.x & 7) * NODES_PER_XCD + (blockIdx.x >> 3) * 4 + wave;
    int c = lane & 15, eo = lane >> 4;
    int cnt_raw = (int)(packed[node] >> 40);
    int cnt = cnt_raw > ELL_CAP ? ELL_CAP : cnt_raw;
    float di = dinv[node];
    const unsigned* row = ell + (size_t)node * ELL_CAP;
    float acc = 0.0f;
    for (int j = eo; j < cnt; j += 4) {
        unsigned ed = row[j];
        int s = ed & 0x1FFFF;
        float wv = (float)(ed >> 17) * (1.0f / WQSCALE);
        float nrm = dinv[s] * wv * di;
        acc = fmaf(nrm, x[(size_t)s * 16 + c], acc);
    }
    acc += __shfl_xor(acc, 16, 64);
    acc += __shfl_xor(acc, 32, 64);
    acc += di * di * x[(size_t)node * 16 + c];
    if (cnt_raw > ELL_CAP) acc += extra[(size_t)node * 16 + c];   // wave-uniform branch
    if (lane < 16) fvs[wave][c] = acc;
    __syncthreads();
    float fv[16];
#pragma unroll
    for (int k = 0; k < 16; k++) fv[k] = fvs[wave][k];
    float a = b1[2 * lane], b = b1[2 * lane + 1];
#pragma unroll
    for (int k = 0; k < 16; k++) {
        float2 wv = *(const float2*)(W1 + k * 128 + 2 * lane);
        a = fmaf(fv[k], wv.x, a);
        b = fmaf(fv[k], wv.y, b);
    }
    o1s[wave][2 * lane + 0] = fmaxf(a, 0.0f);
    o1s[wave][2 * lane + 1] = fmaxf(b, 0.0f);
    __syncthreads();
    int g = lane >> 4;
    float p = 0.0f;
#pragma unroll
    for (int k = 0; k < 32; k++) {
        int kk = g * 32 + k;
        p = fmaf(o1s[wave][kk], W2[kk * 16 + c], p);
    }
    p += __shfl_down(p, 16, 64);
    p += __shfl_down(p, 32, 64);
    if (lane < 16) {
        h2out[(size_t)node * 16 + c] = p;
        out[(size_t)node * 16 + c] = di * di * p + b2[c];
    }
}

// layer-2 neighbor gather: out[node*16+c] += sum nrm*h2[src]  (XCD-aligned)
__global__ __launch_bounds__(256) void k_gather2(const unsigned* __restrict__ ell,
                                                 const ull* __restrict__ packed,
                                                 const float* __restrict__ dinv,
                                                 const float* __restrict__ h2,
                                                 float* __restrict__ out) {
    int wave = threadIdx.x >> 6, lane = threadIdx.x & 63;
    int node = (blockIdx.x & 7) * NODES_PER_XCD + (blockIdx.x >> 3) * 4 + wave;
    int c = lane & 15, eo = lane >> 4;
    int cnt = (int)(packed[node] >> 40);
    if (cnt > ELL_CAP) cnt = ELL_CAP;
    float di = dinv[node];
    const unsigned* row = ell + (size_t)node * ELL_CAP;
    float acc = 0.0f;
    for (int j = eo; j < cnt; j += 4) {
        unsigned ed = row[j];
        int s = ed & 0x1FFFF;
        float wv = (float)(ed >> 17) * (1.0f / WQSCALE);
        float nrm = dinv[s] * wv * di;
        acc = fmaf(nrm, h2[(size_t)s * 16 + c], acc);
    }
    acc += __shfl_xor(acc, 16, 64);
    acc += __shfl_xor(acc, 32, 64);
    if (lane < 16) out[(size_t)node * 16 + c] += acc;
}

// ===================== CSR fallback (round-2) =====================

__global__ void k_init(float* __restrict__ deg, int* __restrict__ cnt) {
    int i = blockIdx.x * blockDim.x + threadIdx.x;
    if (i < N_NODES) { deg[i] = 1.0f; if (cnt) cnt[i] = 0; }
}

__global__ void k_degcnt(const int* __restrict__ dst, const float* __restrict__ w,
                         float* __restrict__ deg, int* __restrict__ cnt) {
    int e = blockIdx.x * blockDim.x + threadIdx.x;
    if (e < N_EDGES) {
        int d = dst[e];
        atomicAdd(&deg[d], w[e]);
        if (cnt) atomicAdd(&cnt[d], 1);
    }
}

__global__ void k_dinv_agg(const float* __restrict__ x, float* __restrict__ deg_dinv,
                           float* __restrict__ agg) {
    int i = blockIdx.x * blockDim.x + threadIdx.x;
    if (i >= N_NODES) return;
    float di = rsqrtf(deg_dinv[i]);
    deg_dinv[i] = di;
    float s = di * di;
    const float4* xr = (const float4*)(x + (size_t)i * 16);
    float4* ar = (float4*)(agg + (size_t)i * 16);
#pragma unroll
    for (int k = 0; k < 4; k++) {
        float4 v = xr[k];
        v.x *= s; v.y *= s; v.z *= s; v.w *= s;
        ar[k] = v;
    }
}

__global__ __launch_bounds__(256) void k_scan1(const int* __restrict__ cnt,
                                               int* __restrict__ rowptr,
                                               int* __restrict__ bsum) {
    __shared__ int ts[256];
    int tid = threadIdx.x;
    int base = blockIdx.x * SCAN_CHUNK + tid * 8;
    int v[8]; int s = 0;
#pragma unroll
    for (int k = 0; k < 8; k++) {
        int idx = base + k;
        v[k] = (idx < N_NODES) ? cnt[idx] : 0;
        s += v[k];
    }
    ts[tid] = s;
    __syncthreads();
    for (int off = 1; off < 256; off <<= 1) {
        int t = (tid >= off) ? ts[tid - off] : 0;
        __syncthreads();
        ts[tid] += t;
        __syncthreads();
    }
    int run = ts[tid] - s;
#pragma unroll
    for (int k = 0; k < 8; k++) {
        int idx = base + k;
        if (idx < N_NODES) rowptr[idx] = run;
        run += v[k];
    }
    if (tid == 255) bsum[blockIdx.x] = ts[255];
}

__global__ void k_scan2(int* __restrict__ bsum) {
    if (threadIdx.x == 0 && blockIdx.x == 0) {
        int run = 0;
        for (int g = 0; g < SCAN_BLOCKS; g++) { int t = bsum[g]; bsum[g] = run; run += t; }
    }
}

__global__ __launch_bounds__(256) void k_scan3(int* __restrict__ rowptr,
                                               const int* __restrict__ bsum) {
    int tid = threadIdx.x;
    int base = blockIdx.x * SCAN_CHUNK + tid * 8;
    int off = bsum[blockIdx.x];
#pragma unroll
    for (int k = 0; k < 8; k++) {
        int idx = base + k;
        if (idx < N_NODES) rowptr[idx] += off;
    }
    if (blockIdx.x == 0 && tid == 0) rowptr[N_NODES] = N_EDGES;
}

__global__ void k_fill(const int* __restrict__ src, const int* __restrict__ dst,
                       const float* __restrict__ w, const float* __restrict__ dinv,
                       const int* __restrict__ rowptr, int* __restrict__ cnt,
                       int2* __restrict__ perm) {
    int e = blockIdx.x * blockDim.x + threadIdx.x;
    if (e >= N_EDGES) return;
    int s = src[e], d = dst[e];
    float nrm = dinv[s] * w[e] * dinv[d];
    int r = atomicSub(&cnt[d], 1) - 1;
    int pos = rowptr[d] + r;
    perm[pos] = make_int2(s, __float_as_int(nrm));
}

__global__ __launch_bounds__(256) void k_gather(const int2* __restrict__ perm,
                                                const int* __restrict__ rowptr,
                                                const float* __restrict__ feat,
                                                float* __restrict__ out) {
    int wave = threadIdx.x >> 6, lane = threadIdx.x & 63;
    int node = blockIdx.x * 4 + wave;
    int c = lane & 15, eo = lane >> 4;
    int beg = rowptr[node], end = rowptr[node + 1];
    float acc = 0.0f;
    for (int j = beg + eo; j < end; j += 4) {
        int2 ed = perm[j];
        acc = fmaf(__int_as_float(ed.y), feat[(size_t)ed.x * 16 + c], acc);
    }
    acc += __shfl_xor(acc, 16, 64);
    acc += __shfl_xor(acc, 32, 64);
    if (lane < 16) out[(size_t)node * 16 + c] += acc;
}

__global__ __launch_bounds__(256) void k_mlp(float* __restrict__ agg,
                                             const float* __restrict__ W1,
                                             const float* __restrict__ b1,
                                             const float* __restrict__ W2,
                                             const float* __restrict__ b2,
                                             const float* __restrict__ dinv,
                                             float* __restrict__ out) {
    __shared__ float o1s[4][128];
    int wave = threadIdx.x >> 6;
    int lane = threadIdx.x & 63;
    int node = blockIdx.x * 4 + wave;
    const float* f = agg + (size_t)node * 16;
    float fv[16];
#pragma unroll
    for (int k = 0; k < 4; k++) {
        float4 v = ((const float4*)f)[k];
        fv[4 * k + 0] = v.x; fv[4 * k + 1] = v.y; fv[4 * k + 2] = v.z; fv[4 * k + 3] = v.w;
    }
    float a = b1[2 * lane], b = b1[2 * lane + 1];
#pragma unroll
    for (int k = 0; k < 16; k++) {
        float2 wv = *(const float2*)(W1 + k * 128 + 2 * lane);
        a = fmaf(fv[k], wv.x, a);
        b = fmaf(fv[k], wv.y, b);
    }
    o1s[wave][2 * lane + 0] = fmaxf(a, 0.0f);
    o1s[wave][2 * lane + 1] = fmaxf(b, 0.0f);
    __syncthreads();
    int c = lane & 15, g = lane >> 4;
    float p = 0.0f;
#pragma unroll
    for (int k = 0; k < 32; k++) {
        int kk = g * 32 + k;
        p = fmaf(o1s[wave][kk], W2[kk * 16 + c], p);
    }
    p += __shfl_down(p, 16, 64);
    p += __shfl_down(p, 32, 64);
    __syncthreads();
    if (lane < 16) {
        float h2v = p;
        agg[(size_t)node * 16 + c] = h2v;
        float di = dinv[node];
        out[(size_t)node * 16 + c] = di * di * h2v + b2[c];
    }
}

__global__ void k_scatter(const int* __restrict__ src, const int* __restrict__ dst,
                          const float* __restrict__ w, const float* __restrict__ dinv,
                          const float* __restrict__ feat, float* __restrict__ out) {
    int t = blockIdx.x * blockDim.x + threadIdx.x;
    int e = t >> 2;
    int c4 = (t & 3) * 4;
    if (e >= N_EDGES) return;
    int s = src[e], d = dst[e];
    float nrm = dinv[s] * w[e] * dinv[d];
    float4 v = *(const float4*)(feat + (size_t)s * 16 + c4);
    float* o = out + (size_t)d * 16 + c4;
    atomicAdd(o + 0, nrm * v.x);
    atomicAdd(o + 1, nrm * v.y);
    atomicAdd(o + 2, nrm * v.z);
    atomicAdd(o + 3, nrm * v.w);
}

// ===================== launch =====================

extern "C" void kernel_launch(void* const* d_in, const int* in_sizes, int n_in,
                              void* d_out, int out_size, void* d_ws, size_t ws_size,
                              hipStream_t stream) {
    const float* x  = (const float*)d_in[0];
    const int*   ei = (const int*)d_in[1];
    const float* w  = (const float*)d_in[2];
    const float* W1 = (const float*)d_in[3];
    const float* b1 = (const float*)d_in[4];
    const float* W2 = (const float*)d_in[5];
    const float* b2 = (const float*)d_in[6];
    float* out = (float*)d_out;

    const int* src = ei;
    const int* dst = ei + N_EDGES;
    const int B = 256;

    // ---- ELL workspace layout (all 16B-aligned offsets) ----
    char* p = (char*)d_ws;
    ull*      packed = (ull*)p;            p += (size_t)N_PAD * 8;
    unsigned* ell    = (unsigned*)p;       p += (size_t)N_NODES * ELL_CAP * 4;
    float*    dinv   = (float*)p;          p += (size_t)N_PAD * 4;
    float*    extra  = (float*)p;          p += (size_t)N_NODES * 16 * 4;
    float*    h2     = (float*)p;          p += (size_t)N_NODES * 16 * 4;
    int*      ovs    = (int*)p;            p += (size_t)OVF_MAX * 4;
    int*      ovd    = (int*)p;            p += (size_t)OVF_MAX * 4;
    float*    ovw    = (float*)p;          p += (size_t)OVF_MAX * 4;
    int*      ovf_cnt = (int*)p;           p += 16;
    const size_t WS_ELL = (size_t)(p - (char*)d_ws);

    if (ws_size >= WS_ELL) {
        const int chunkB = (N_EDGES + 2048 - 1) / 2048;   // 1563: 8 edges/thread per chunk
        const int buildB = chunkB * XCDS;                 // x8 XCD-filtered passes
        k_zero<<<(N_NODES * 4 + B - 1) / B, B, 0, stream>>>(packed, (float4*)extra, ovf_cnt);
        k_build<<<buildB, B, 0, stream>>>(src, dst, w, packed, ell, ovs, ovd, ovw, ovf_cnt);
        k_node<<<(N_NODES + B - 1) / B, B, 0, stream>>>(packed, dinv);
        k_ovf<<<64, B, 0, stream>>>(ovs, ovd, ovw, ovf_cnt, dinv, x, extra);
        k_gather_mlp<<<N_NODES / 4, B, 0, stream>>>(ell, packed, dinv, x, extra,
                                                    W1, b1, W2, b2, h2, out);
        k_gather2<<<N_NODES / 4, B, 0, stream>>>(ell, packed, dinv, h2, out);
        k_ovf<<<64, B, 0, stream>>>(ovs, ovd, ovw, ovf_cnt, dinv, h2, out);
        return;
    }

    // ---- CSR fallback (round-2 path) ----
    float* deg_dinv = (float*)d_ws;
    int*   cnt      = (int*)(deg_dinv + N_PAD);
    int*   rowptr   = cnt + N_PAD;
    int*   bsum     = rowptr + N_PAD;
    float* agg      = (float*)(bsum + 64);
    int2*  perm     = (int2*)(agg + (size_t)N_NODES * 16);
    const size_t WS_CSR = ((size_t)N_PAD * 3 + 64 + (size_t)N_NODES * 16) * 4
                          + (size_t)N_EDGES * 8;

    if (ws_size >= WS_CSR) {
        k_init<<<(N_NODES + B - 1) / B, B, 0, stream>>>(deg_dinv, cnt);
        k_degcnt<<<(N_EDGES + B - 1) / B, B, 0, stream>>>(dst, w, deg_dinv, cnt);
        k_dinv_agg<<<(N_NODES + B - 1) / B, B, 0, stream>>>(x, deg_dinv, agg);
        k_scan1<<<SCAN_BLOCKS, 256, 0, stream>>>(cnt, rowptr, bsum);
        k_scan2<<<1, 64, 0, stream>>>(bsum);
        k_scan3<<<SCAN_BLOCKS, 256, 0, stream>>>(rowptr, bsum);
        k_fill<<<(N_EDGES + B - 1) / B, B, 0, stream>>>(src, dst, w, deg_dinv,
                                                        rowptr, cnt, perm);
        k_gather<<<N_NODES / 4, B, 0, stream>>>(perm, rowptr, x, agg);
        k_mlp<<<N_NODES / 4, B, 0, stream>>>(agg, W1, b1, W2, b2, deg_dinv, out);
        k_gather<<<N_NODES / 4, B, 0, stream>>>(perm, rowptr, agg, out);
    } else {
        float* deg = (float*)d_ws;
        float* ag  = (float*)d_ws + N_NODES;
        k_init<<<(N_NODES + B - 1) / B, B, 0, stream>>>(deg, (int*)nullptr);
        k_degcnt<<<(N_EDGES + B - 1) / B, B, 0, stream>>>(dst, w, deg, (int*)nullptr);
        k_dinv_agg<<<(N_NODES + B - 1) / B, B, 0, stream>>>(x, deg, ag);
        k_scatter<<<((size_t)N_EDGES * 4 + B - 1) / B, B, 0, stream>>>(src, dst, w, deg, x, ag);
        k_mlp<<<N_NODES / 4, B, 0, stream>>>(ag, W1, b1, W2, b2, deg, out);
        k_scatter<<<((size_t)N_EDGES * 4 + B - 1) / B, B, 0, stream>>>(src, dst, w, deg, ag, out);
    }
}